// Round 3
// baseline (195.596 us; speedup 1.0000x reference)
//
#include <hip/hip_runtime.h>

// Problem: B=2, S=2048, D=1024, H=16, HD=64. fp32 in/out.
// Pipeline exploits head-summed K/V: k_sum = x @ (sum_h Wk_h)^T + sum_h bk_h.
//  1. prep_all:    x, Wout -> f16; wcomb = [Wq; Wred] f16 (1152x1024); bcomb
//  2. gemm_t2<0>:  [Q*scale | k_sum | v_sum^T] = x @ wcomb^T + bcomb (N=1152)
//  3. flash_attn10: 8 rows/block, one wave = one full s-row, 128-t batched
//                  softmax, reader-linear P layout, paired chunks (17 units)
//  4. gemm_t2<1>:  out = ao @ Wout^T + bout   (4096x1024x1024) -> f32

#define S_LEN 2048
#define DIM 1024

using floatx4 = __attribute__((ext_vector_type(4))) float;
using halfx8  = __attribute__((ext_vector_type(8))) _Float16;
using halfx4  = __attribute__((ext_vector_type(4))) _Float16;

__device__ __forceinline__ floatx4 mfma16(halfx8 a, halfx8 b, floatx4 c) {
  return __builtin_amdgcn_mfma_f32_16x16x32_f16(a, b, c, 0, 0, 0);
}

// async global->LDS, 16B per lane; lds dst is wave-uniform base + lane*16
__device__ __forceinline__ void gll16(const void* g, void* l) {
  __builtin_amdgcn_global_load_lds(
      (const __attribute__((address_space(1))) void*)g,
      (__attribute__((address_space(3))) void*)l, 16, 0, 0);
}

// ---------------- prep: conversions + combined weights ----------------
__global__ __launch_bounds__(256) void prep_all(
    const float* __restrict__ x, const float* __restrict__ wqkv,
    const float* __restrict__ bqkv, const float* __restrict__ wout,
    _Float16* __restrict__ xb, _Float16* __restrict__ wcomb,
    _Float16* __restrict__ woutb, float* __restrict__ bcomb) {
  int bx = blockIdx.x;
  if (bx < 6144) {
    size_t i4 = ((size_t)bx * 256 + threadIdx.x) * 4;
    const float* src;
    _Float16* dst;
    size_t off;
    if (i4 < 4194304) { src = x; dst = xb; off = i4; }
    else if (i4 < 5242880) { src = wqkv; dst = wcomb; off = i4 - 4194304; }
    else { src = wout; dst = woutb; off = i4 - 5242880; }
    float4 v = *(const float4*)(src + off);
    halfx4 o;
    o[0] = (_Float16)v.x; o[1] = (_Float16)v.y;
    o[2] = (_Float16)v.z; o[3] = (_Float16)v.w;
    *(halfx4*)(dst + off) = o;
  } else {
    int gid = (bx - 6144) * 256 + threadIdx.x;  // 131072 threads
    int c = gid >> 10, j = gid & 1023;
    int row0 = (c < 64) ? (1024 + c) : (2048 + c - 64);
    float s = 0.f;
#pragma unroll
    for (int h = 0; h < 16; ++h) s += wqkv[(size_t)(row0 + h * 64) * 1024 + j];
    wcomb[(size_t)1024 * 1024 + gid] = (_Float16)s;
    if (gid < 1024) bcomb[gid] = bqkv[gid];
    if (gid < 128) {
      int b0 = (gid < 64) ? (1024 + gid) : (2048 + gid - 64);
      float sb = 0.f;
#pragma unroll
      for (int h = 0; h < 16; ++h) sb += bqkv[b0 + h * 64];
      bcomb[1024 + gid] = sb;
    }
  }
}

// ------- gemm_t2: 128M x 128N tile (m97-style), BK=64, 2 barriers/step -----
// Wave w -> 64x64 quadrant: rows (w&1)*64, cols (w>>1)*64; 4x4 16x16 frags.
// gll16 staging with XOR col-group swizzle (row r group g at g^(r&7)).
// MODE 0: N=1152 fused epilogue -> qb (*scale), kb, vtb(V^T). MODE 1: f32 out.
template <int MODE>
__global__ __launch_bounds__(256, 2) void gemm_t2(
    const _Float16* __restrict__ A, const _Float16* __restrict__ W,
    const float* __restrict__ bias, void* __restrict__ Cv,
    _Float16* __restrict__ kbo, _Float16* __restrict__ vto) {
  const int K = 1024;
  __shared__ _Float16 As[128][64];  // 16 KB
  __shared__ _Float16 Ws[128][64];  // 16 KB
  int tid = threadIdx.x;
  int lane = tid & 63, w = tid >> 6, ln = lane & 15, q4 = lane >> 4;
  int m0 = blockIdx.x * 128, n0 = blockIdx.y * 128;
  int mh = (w & 1) * 64, nh = (w >> 1) * 64;
  int rr = lane >> 3, gg = ((lane & 7) ^ rr) * 8;  // staging lane row/col
  const _Float16* agp = A + (size_t)(m0 + w * 32 + rr) * K + gg;
  const _Float16* wgp = W + (size_t)(n0 + w * 32 + rr) * K + gg;
  floatx4 acc[4][4] = {};
  for (int kt = 0; kt < K; kt += 64) {
    __syncthreads();  // readers done with previous tile
#pragma unroll
    for (int j = 0; j < 4; ++j) {
      gll16(agp + (size_t)(8 * j) * K + kt, &As[w * 32 + 8 * j][0]);
      gll16(wgp + (size_t)(8 * j) * K + kt, &Ws[w * 32 + 8 * j][0]);
    }
    __syncthreads();  // staging visible
#pragma unroll
    for (int kh = 0; kh < 2; ++kh) {
      int sw = ((q4 + 4 * kh) ^ (ln & 7)) * 8;
      halfx8 bf[4];
#pragma unroll
      for (int nf = 0; nf < 4; ++nf)
        bf[nf] = *(const halfx8*)&Ws[nh + nf * 16 + ln][sw];
#pragma unroll
      for (int mf = 0; mf < 4; ++mf) {
        halfx8 af = *(const halfx8*)&As[mh + mf * 16 + ln][sw];
#pragma unroll
        for (int nf = 0; nf < 4; ++nf)
          acc[mf][nf] = mfma16(af, bf[nf], acc[mf][nf]);
      }
    }
  }
  const float qscale = 0.18033688011112042f;  // (1/sqrt(64)) * log2(e)
#pragma unroll
  for (int nf = 0; nf < 4; ++nf) {
    int col = n0 + nh + nf * 16 + ln;
    float bv = bias[col];
    if constexpr (MODE == 1) {
#pragma unroll
      for (int mf = 0; mf < 4; ++mf)
#pragma unroll
        for (int i = 0; i < 4; ++i) {
          int row = m0 + mh + mf * 16 + q4 * 4 + i;
          ((float*)Cv)[(size_t)row * 1024 + col] = acc[mf][nf][i] + bv;
        }
    } else {
      if (col < 1024) {  // Q, pre-scaled for log2-domain softmax
#pragma unroll
        for (int mf = 0; mf < 4; ++mf)
#pragma unroll
          for (int i = 0; i < 4; ++i) {
            int row = m0 + mh + mf * 16 + q4 * 4 + i;
            ((_Float16*)Cv)[(size_t)row * 1024 + col] =
                (_Float16)((acc[mf][nf][i] + bv) * qscale);
          }
      } else if (col < 1088) {  // k_sum
        int ck = col - 1024;
#pragma unroll
        for (int mf = 0; mf < 4; ++mf)
#pragma unroll
          for (int i = 0; i < 4; ++i) {
            int row = m0 + mh + mf * 16 + q4 * 4 + i;
            kbo[(size_t)row * 64 + ck] = (_Float16)(acc[mf][nf][i] + bv);
          }
      } else {  // v_sum, transposed: vtb[(b*64+d)*S + s]
        int d = col - 1088;
#pragma unroll
        for (int mf = 0; mf < 4; ++mf) {
          int row0 = m0 + mh + mf * 16 + q4 * 4;
          int bb = row0 >> 11, sps = row0 & 2047;
          halfx4 o;
#pragma unroll
          for (int i = 0; i < 4; ++i) o[i] = (_Float16)(acc[mf][nf][i] + bv);
          *(halfx4*)&vto[((size_t)((bb << 6) + d)) * S_LEN + sps] = o;
        }
      }
    }
  }
}

// ---------------- flash v10: 1 wave = 1 full s-row, 128-t batched ----------
// Block = 8 consecutive s-rows (one chunk of 8), 8 waves. Each wave processes
// the whole 128-t staged tile per iteration: 16 QK MFMA -> one batched
// softmax (31-fmax tree, 32 exp2, single defer-check) -> 16 PV MFMA.
// 8 rows amortize each staged tile (2x v9), no merge epilogue.
// P layout reader-linear: half-idx ((t>>3)*16 + h)*8 + (t&7) -> the 4 PV
// b128 reads are lane-linear (conflict-free); writes 8B, ~4-way (cheap).
// Chunks c paired (c, 255-p): nt(c)+nt(255-c) == 17 for all c -> grid 512,
// exactly 2 blocks/CU, zero imbalance. LDS 64K -> 2 blocks/CU.
__global__ __launch_bounds__(512, 4) void flash_attn10(
    const _Float16* __restrict__ Qb, const _Float16* __restrict__ kb,
    const _Float16* __restrict__ vtb, _Float16* __restrict__ aob) {
  __shared__ _Float16 Ks[128][64];   // 16 KB  K tile [t][d], XOR-swizzled
  __shared__ _Float16 Vt[64][128];   // 16 KB  V^T tile [d][t], per-64-half swz
  __shared__ _Float16 Ps[8][2048];   // 32 KB  per-wave P, reader-linear
  int tid = threadIdx.x;
  int lane = tid & 63, w = tid >> 6, ln = lane & 15, q4 = lane >> 4;
  int bx = (int)blockIdx.x;
  int p = bx >> 1, b = bx & 1;
  size_t bS = (size_t)b * S_LEN;

  // K staging: wave w covers t-rows w*16..+15; lane: row += lane>>3, grp^row
  int rr = lane >> 3, ggk = ((lane & 7) ^ rr) * 8;
  const _Float16* kgp = kb + (bS + w * 16 + rr) * 64 + ggk;
  // V staging: wave w covers d-rows w*8..+7; lane: row += lane>>4,
  // t-col = half*64 + (vg ^ (row&7))*8, vg = lane&7, half = (lane>>3)&1
  int vr = lane >> 4;
  int vhalf = (lane >> 3) & 1, vg = lane & 7;
  const _Float16* vgp[2];
#pragma unroll
  for (int j = 0; j < 2; ++j) {
    int row = w * 8 + 4 * j + vr;
    vgp[j] = vtb + ((size_t)b * 64 + row) * S_LEN + vhalf * 64 +
             ((vg ^ (row & 7)) * 8);
  }
  int swk0 = (q4 ^ (ln & 7)) * 8;
  int swk1 = ((q4 + 4) ^ (ln & 7)) * 8;
  _Float16* Pw = &Ps[w][0];
  // P write (halfx4): half-idx = (tq*8+tf*2)*128 + pwbase
  int pwbase = (q4 >> 1) * 128 + ln * 8 + (q4 & 1) * 4;
  // P read (halfx8): half-idx = kc*512 + prbase  (lane-linear)
  int prbase = q4 * 128 + ln * 8;

  for (int pass = 0; pass < 2; ++pass) {
    int c = pass ? (255 - p) : p;
    int s0 = c * 8;
    int s = s0 + w;

    const _Float16* qp = Qb + (bS + s) * DIM + ln * 64 + q4 * 8;
    halfx8 bq0 = *(const halfx8*)qp, bq1 = *(const halfx8*)(qp + 32);

    float m_run = -1e30f, l_run = 0.f;
    floatx4 oacc[4] = {};
    int nt = (c >> 4) + 1;

    for (int it = 0; it < nt; ++it) {
      int t0 = it << 7;
      __syncthreads();
      gll16(kgp + (size_t)t0 * 64, &Ks[w * 16][0]);
      gll16(kgp + (size_t)(t0 + 8) * 64, &Ks[w * 16 + 8][0]);
      gll16(vgp[0] + t0, &Vt[w * 8][0]);
      gll16(vgp[1] + t0, &Vt[w * 8 + 4][0]);
      __syncthreads();

      // S^T = K Q^T (log2 domain): frag (tq,tf) rows t = t0+tq*64+tf*16+ln
      floatx4 sf[2][4];
      __builtin_amdgcn_s_setprio(1);
#pragma unroll
      for (int tq = 0; tq < 2; ++tq)
#pragma unroll
        for (int tf = 0; tf < 4; ++tf) {
          halfx8 ak0 = *(const halfx8*)&Ks[tq * 64 + tf * 16 + ln][swk0];
          halfx8 ak1 = *(const halfx8*)&Ks[tq * 64 + tf * 16 + ln][swk1];
          floatx4 z = {};
          z = mfma16(ak0, bq0, z);
          sf[tq][tf] = mfma16(ak1, bq1, z);
        }
      __builtin_amdgcn_s_setprio(0);
      if (it == nt - 1) {  // causal mask (block-uniform: only final tile)
#pragma unroll
        for (int tq = 0; tq < 2; ++tq)
#pragma unroll
          for (int tf = 0; tf < 4; ++tf)
#pragma unroll
            for (int i = 0; i < 4; ++i) {
              int t = t0 + tq * 64 + tf * 16 + q4 * 4 + i;
              if (t > s) sf[tq][tf][i] = -1e30f;
            }
      }
      // batched max over all 32 values
      float tm = -1e30f;
#pragma unroll
      for (int tq = 0; tq < 2; ++tq)
#pragma unroll
        for (int tf = 0; tf < 4; ++tf)
          tm = fmaxf(tm, fmaxf(fmaxf(sf[tq][tf][0], sf[tq][tf][1]),
                               fmaxf(sf[tq][tf][2], sf[tq][tf][3])));
      tm = fmaxf(tm, __shfl_xor(tm, 16));
      tm = fmaxf(tm, __shfl_xor(tm, 32));
      // defer-rescale (T13): skip O/l rescale while max drift <= 8 (log2)
      if (!__all(tm <= m_run + 8.f)) {
        float mn = fmaxf(m_run, tm);
        float alpha = exp2f(m_run - mn);
        m_run = mn;
        l_run *= alpha;
#pragma unroll
        for (int n2 = 0; n2 < 4; ++n2)
#pragma unroll
          for (int i = 0; i < 4; ++i) oacc[n2][i] *= alpha;
      }
      float rs = 0.f;
#pragma unroll
      for (int tq = 0; tq < 2; ++tq)
#pragma unroll
        for (int tf = 0; tf < 4; ++tf) {
          float p0 = exp2f(sf[tq][tf][0] - m_run);
          float p1 = exp2f(sf[tq][tf][1] - m_run);
          float p2 = exp2f(sf[tq][tf][2] - m_run);
          float p3 = exp2f(sf[tq][tf][3] - m_run);
          rs += (p0 + p1) + (p2 + p3);
          halfx4 pk;
          pk[0] = (_Float16)p0; pk[1] = (_Float16)p1;
          pk[2] = (_Float16)p2; pk[3] = (_Float16)p3;
          *(halfx4*)&Pw[(tq * 8 + tf * 2) * 128 + pwbase] = pk;
        }
      rs += __shfl_xor(rs, 16);
      rs += __shfl_xor(rs, 32);
      l_run += rs;
      // PV: O^T += V^T x P over 4 k-chunks of 32 t
      halfx8 bp[4];
#pragma unroll
      for (int kc = 0; kc < 4; ++kc)
        bp[kc] = *(const halfx8*)&Pw[kc * 512 + prbase];
      __builtin_amdgcn_s_setprio(1);
#pragma unroll
      for (int kc = 0; kc < 4; ++kc) {
        int half = (kc >> 1) * 64;
        int sw = ((q4 + 4 * (kc & 1)) ^ (ln & 7)) * 8;
#pragma unroll
        for (int n2 = 0; n2 < 4; ++n2) {
          halfx8 av = *(const halfx8*)&Vt[n2 * 16 + ln][half + sw];
          oacc[n2] = mfma16(av, bp[kc], oacc[n2]);
        }
      }
      __builtin_amdgcn_s_setprio(0);
    }
    // epilogue: O^T frag n2: h=ln, d=n2*16+q4*4+i (wave owns the full row)
    float inv = 1.0f / l_run;
#pragma unroll
    for (int n2 = 0; n2 < 4; ++n2) {
      halfx4 o;
#pragma unroll
      for (int i = 0; i < 4; ++i) o[i] = (_Float16)(oacc[n2][i] * inv);
      *(halfx4*)(aob + (bS + s) * DIM + ln * 64 + n2 * 16 + q4 * 4) = o;
    }
  }
}

extern "C" void kernel_launch(void* const* d_in, const int* in_sizes, int n_in,
                              void* d_out, int out_size, void* d_ws,
                              size_t ws_size, hipStream_t stream) {
  const float* x    = (const float*)d_in[0];
  const float* wqkv = (const float*)d_in[1];
  const float* bqkv = (const float*)d_in[2];
  const float* wout = (const float*)d_in[3];
  const float* bout = (const float*)d_in[4];
  float* out = (float*)d_out;
  char* ws = (char*)d_ws;
  _Float16* xb    = (_Float16*)(ws);                               // 8 MB
  _Float16* qb    = (_Float16*)(ws + (8u << 20));                  // 8 MB
  _Float16* aob   = (_Float16*)(ws + (16u << 20));                 // 8 MB
  _Float16* kb    = (_Float16*)(ws + (24u << 20));                 // 512 KB
  _Float16* vtb   = (_Float16*)(ws + (24u << 20) + (512u << 10));  // 512 KB
  _Float16* wcomb = (_Float16*)(ws + (25u << 20));                 // 2.25 MB
  _Float16* woutb = (_Float16*)(ws + (27u << 20) + (512u << 10));  // 2 MB
  float*    bcomb = (float*)(ws + (29u << 20) + (512u << 10));     // 4.6 KB

  hipLaunchKernelGGL(prep_all, dim3(6656), dim3(256), 0, stream,
                     x, wqkv, bqkv, wout, xb, wcomb, woutb, bcomb);
  hipLaunchKernelGGL((gemm_t2<0>), dim3(32, 9), dim3(256), 0, stream,
                     xb, wcomb, bcomb, (void*)qb, kb, vtb);
  hipLaunchKernelGGL(flash_attn10, dim3(512), dim3(512), 0, stream,
                     qb, kb, vtb, aob);
  hipLaunchKernelGGL((gemm_t2<1>), dim3(32, 8), dim3(256), 0, stream,
                     aob, woutb, bout, (void*)out, nullptr, nullptr);
}

// Round 4
// 174.534 us; speedup vs baseline: 1.1207x; 1.1207x over previous
//
#include <hip/hip_runtime.h>

// Problem: B=2, S=2048, D=1024, H=16, HD=64. fp32 in/out.
// Pipeline exploits head-summed K/V: k_sum = x @ (sum_h Wk_h)^T + sum_h bk_h.
//  1. prep_all:    x, Wout -> f16; wcomb = [Wq; Wred] f16 (1152x1024); bcomb
//  2. gemm_t2<0>:  [Q*scale | k_sum | v_sum^T] = x @ wcomb^T + bcomb (N=1152)
//  3. flash_attn11: 8 rows/block, 1 wave = 1 full s-row, 128-t batched
//                  softmax; ONE chunk per block, grid 512, interleaved
//                  dispatch order for CU-level load balance (17 units/CU)
//  4. gemm_t2<1>:  out = ao @ Wout^T + bout   (4096x1024x1024) -> f32

#define S_LEN 2048
#define DIM 1024

using floatx4 = __attribute__((ext_vector_type(4))) float;
using halfx8  = __attribute__((ext_vector_type(8))) _Float16;
using halfx4  = __attribute__((ext_vector_type(4))) _Float16;

__device__ __forceinline__ floatx4 mfma16(halfx8 a, halfx8 b, floatx4 c) {
  return __builtin_amdgcn_mfma_f32_16x16x32_f16(a, b, c, 0, 0, 0);
}

// async global->LDS, 16B per lane; lds dst is wave-uniform base + lane*16
__device__ __forceinline__ void gll16(const void* g, void* l) {
  __builtin_amdgcn_global_load_lds(
      (const __attribute__((address_space(1))) void*)g,
      (__attribute__((address_space(3))) void*)l, 16, 0, 0);
}

// ---------------- prep: conversions + combined weights ----------------
__global__ __launch_bounds__(256) void prep_all(
    const float* __restrict__ x, const float* __restrict__ wqkv,
    const float* __restrict__ bqkv, const float* __restrict__ wout,
    _Float16* __restrict__ xb, _Float16* __restrict__ wcomb,
    _Float16* __restrict__ woutb, float* __restrict__ bcomb) {
  int bx = blockIdx.x;
  if (bx < 6144) {
    size_t i4 = ((size_t)bx * 256 + threadIdx.x) * 4;
    const float* src;
    _Float16* dst;
    size_t off;
    if (i4 < 4194304) { src = x; dst = xb; off = i4; }
    else if (i4 < 5242880) { src = wqkv; dst = wcomb; off = i4 - 4194304; }
    else { src = wout; dst = woutb; off = i4 - 5242880; }
    float4 v = *(const float4*)(src + off);
    halfx4 o;
    o[0] = (_Float16)v.x; o[1] = (_Float16)v.y;
    o[2] = (_Float16)v.z; o[3] = (_Float16)v.w;
    *(halfx4*)(dst + off) = o;
  } else {
    int gid = (bx - 6144) * 256 + threadIdx.x;  // 131072 threads
    int c = gid >> 10, j = gid & 1023;
    int row0 = (c < 64) ? (1024 + c) : (2048 + c - 64);
    float s = 0.f;
#pragma unroll
    for (int h = 0; h < 16; ++h) s += wqkv[(size_t)(row0 + h * 64) * 1024 + j];
    wcomb[(size_t)1024 * 1024 + gid] = (_Float16)s;
    if (gid < 1024) bcomb[gid] = bqkv[gid];
    if (gid < 128) {
      int b0 = (gid < 64) ? (1024 + gid) : (2048 + gid - 64);
      float sb = 0.f;
#pragma unroll
      for (int h = 0; h < 16; ++h) sb += bqkv[b0 + h * 64];
      bcomb[1024 + gid] = sb;
    }
  }
}

// ------- gemm_t2: 128M x 128N tile (m97-style), BK=64, 2 barriers/step -----
// Wave w -> 64x64 quadrant: rows (w&1)*64, cols (w>>1)*64; 4x4 16x16 frags.
// gll16 staging with XOR col-group swizzle (row r group g at g^(r&7)).
// MODE 0: N=1152 fused epilogue -> qb (*scale), kb, vtb(V^T). MODE 1: f32 out.
template <int MODE>
__global__ __launch_bounds__(256, 2) void gemm_t2(
    const _Float16* __restrict__ A, const _Float16* __restrict__ W,
    const float* __restrict__ bias, void* __restrict__ Cv,
    _Float16* __restrict__ kbo, _Float16* __restrict__ vto) {
  const int K = 1024;
  __shared__ _Float16 As[128][64];  // 16 KB
  __shared__ _Float16 Ws[128][64];  // 16 KB
  int tid = threadIdx.x;
  int lane = tid & 63, w = tid >> 6, ln = lane & 15, q4 = lane >> 4;
  int m0 = blockIdx.x * 128, n0 = blockIdx.y * 128;
  int mh = (w & 1) * 64, nh = (w >> 1) * 64;
  int rr = lane >> 3, gg = ((lane & 7) ^ rr) * 8;  // staging lane row/col
  const _Float16* agp = A + (size_t)(m0 + w * 32 + rr) * K + gg;
  const _Float16* wgp = W + (size_t)(n0 + w * 32 + rr) * K + gg;
  floatx4 acc[4][4] = {};
  for (int kt = 0; kt < K; kt += 64) {
    __syncthreads();  // readers done with previous tile
#pragma unroll
    for (int j = 0; j < 4; ++j) {
      gll16(agp + (size_t)(8 * j) * K + kt, &As[w * 32 + 8 * j][0]);
      gll16(wgp + (size_t)(8 * j) * K + kt, &Ws[w * 32 + 8 * j][0]);
    }
    __syncthreads();  // staging visible
#pragma unroll
    for (int kh = 0; kh < 2; ++kh) {
      int sw = ((q4 + 4 * kh) ^ (ln & 7)) * 8;
      halfx8 bf[4];
#pragma unroll
      for (int nf = 0; nf < 4; ++nf)
        bf[nf] = *(const halfx8*)&Ws[nh + nf * 16 + ln][sw];
#pragma unroll
      for (int mf = 0; mf < 4; ++mf) {
        halfx8 af = *(const halfx8*)&As[mh + mf * 16 + ln][sw];
#pragma unroll
        for (int nf = 0; nf < 4; ++nf)
          acc[mf][nf] = mfma16(af, bf[nf], acc[mf][nf]);
      }
    }
  }
  const float qscale = 0.18033688011112042f;  // (1/sqrt(64)) * log2(e)
#pragma unroll
  for (int nf = 0; nf < 4; ++nf) {
    int col = n0 + nh + nf * 16 + ln;
    float bv = bias[col];
    if constexpr (MODE == 1) {
#pragma unroll
      for (int mf = 0; mf < 4; ++mf)
#pragma unroll
        for (int i = 0; i < 4; ++i) {
          int row = m0 + mh + mf * 16 + q4 * 4 + i;
          ((float*)Cv)[(size_t)row * 1024 + col] = acc[mf][nf][i] + bv;
        }
    } else {
      if (col < 1024) {  // Q, pre-scaled for log2-domain softmax
#pragma unroll
        for (int mf = 0; mf < 4; ++mf)
#pragma unroll
          for (int i = 0; i < 4; ++i) {
            int row = m0 + mh + mf * 16 + q4 * 4 + i;
            ((_Float16*)Cv)[(size_t)row * 1024 + col] =
                (_Float16)((acc[mf][nf][i] + bv) * qscale);
          }
      } else if (col < 1088) {  // k_sum
        int ck = col - 1024;
#pragma unroll
        for (int mf = 0; mf < 4; ++mf)
#pragma unroll
          for (int i = 0; i < 4; ++i) {
            int row = m0 + mh + mf * 16 + q4 * 4 + i;
            kbo[(size_t)row * 64 + ck] = (_Float16)(acc[mf][nf][i] + bv);
          }
      } else {  // v_sum, transposed: vtb[(b*64+d)*S + s]
        int d = col - 1088;
#pragma unroll
        for (int mf = 0; mf < 4; ++mf) {
          int row0 = m0 + mh + mf * 16 + q4 * 4;
          int bb = row0 >> 11, sps = row0 & 2047;
          halfx4 o;
#pragma unroll
          for (int i = 0; i < 4; ++i) o[i] = (_Float16)(acc[mf][nf][i] + bv);
          *(halfx4*)&vto[((size_t)((bb << 6) + d)) * S_LEN + sps] = o;
        }
      }
    }
  }
}

// ---------------- flash v11: 1 wave = 1 full s-row, one chunk/block --------
// Block = 8 consecutive s-rows (one chunk), 8 waves. Each wave processes the
// whole 128-t staged tile per iteration: 16 QK MFMA -> one batched softmax
// (31-fmax tree, 32 exp2, single defer-check) -> 16 PV MFMA.
// Grid 512 = all chunk-instances (256 row-chunks x 2 batches), each EXACTLY
// once (v10 double-covered chunks). Interleaved dispatch: block bx -> chunk
// g = bx&1 ? 511-(bx>>1) : bx>>1, so consecutive block pairs sum to 17
// staging units -> balanced 2-blocks/CU under sequential dispatch.
// P layout reader-linear: half-idx ((t>>3)*16 + h)*8 + (t&7).
__global__ __launch_bounds__(512, 4) void flash_attn11(
    const _Float16* __restrict__ Qb, const _Float16* __restrict__ kb,
    const _Float16* __restrict__ vtb, _Float16* __restrict__ aob) {
  __shared__ _Float16 Ks[128][64];   // 16 KB  K tile [t][d], XOR-swizzled
  __shared__ _Float16 Vt[64][128];   // 16 KB  V^T tile [d][t], per-64-half swz
  __shared__ _Float16 Ps[8][2048];   // 32 KB  per-wave P, reader-linear
  int tid = threadIdx.x;
  int lane = tid & 63, w = tid >> 6, ln = lane & 15, q4 = lane >> 4;
  int bx = (int)blockIdx.x;
  int g = (bx & 1) ? (511 - (bx >> 1)) : (bx >> 1);  // global chunk, bijective
  int b = g >> 8;           // batch
  int crow = g & 255;       // row-chunk within batch
  int s0 = crow * 8;
  int s = s0 + w;
  size_t bS = (size_t)b * S_LEN;

  // K staging: wave w covers t-rows w*16..+15; lane: row += lane>>3, grp^row
  int rr = lane >> 3, ggk = ((lane & 7) ^ rr) * 8;
  const _Float16* kgp = kb + (bS + w * 16 + rr) * 64 + ggk;
  // V staging: wave w covers d-rows w*8..+7; lane: row += lane>>4,
  // t-col = half*64 + (vg ^ (row&7))*8, vg = lane&7, half = (lane>>3)&1
  int vr = lane >> 4;
  int vhalf = (lane >> 3) & 1, vg = lane & 7;
  const _Float16* vgp[2];
#pragma unroll
  for (int j = 0; j < 2; ++j) {
    int row = w * 8 + 4 * j + vr;
    vgp[j] = vtb + ((size_t)b * 64 + row) * S_LEN + vhalf * 64 +
             ((vg ^ (row & 7)) * 8);
  }
  int swk0 = (q4 ^ (ln & 7)) * 8;
  int swk1 = ((q4 + 4) ^ (ln & 7)) * 8;
  _Float16* Pw = &Ps[w][0];
  // P write (halfx4): half-idx = (tq*8+tf*2)*128 + pwbase
  int pwbase = (q4 >> 1) * 128 + ln * 8 + (q4 & 1) * 4;
  // P read (halfx8): half-idx = kc*512 + prbase  (lane-linear)
  int prbase = q4 * 128 + ln * 8;

  const _Float16* qp = Qb + (bS + s) * DIM + ln * 64 + q4 * 8;
  halfx8 bq0 = *(const halfx8*)qp, bq1 = *(const halfx8*)(qp + 32);

  float m_run = -1e30f, l_run = 0.f;
  floatx4 oacc[4] = {};
  int nt = (crow >> 4) + 1;

  for (int it = 0; it < nt; ++it) {
    int t0 = it << 7;
    __syncthreads();
    gll16(kgp + (size_t)t0 * 64, &Ks[w * 16][0]);
    gll16(kgp + (size_t)(t0 + 8) * 64, &Ks[w * 16 + 8][0]);
    gll16(vgp[0] + t0, &Vt[w * 8][0]);
    gll16(vgp[1] + t0, &Vt[w * 8 + 4][0]);
    __syncthreads();

    // S^T = K Q^T (log2 domain): frag (tq,tf) rows t = t0+tq*64+tf*16+ln
    floatx4 sf[2][4];
    __builtin_amdgcn_s_setprio(1);
#pragma unroll
    for (int tq = 0; tq < 2; ++tq)
#pragma unroll
      for (int tf = 0; tf < 4; ++tf) {
        halfx8 ak0 = *(const halfx8*)&Ks[tq * 64 + tf * 16 + ln][swk0];
        halfx8 ak1 = *(const halfx8*)&Ks[tq * 64 + tf * 16 + ln][swk1];
        floatx4 z = {};
        z = mfma16(ak0, bq0, z);
        sf[tq][tf] = mfma16(ak1, bq1, z);
      }
    __builtin_amdgcn_s_setprio(0);
    if (it == nt - 1) {  // causal mask (block-uniform: only final tile)
#pragma unroll
      for (int tq = 0; tq < 2; ++tq)
#pragma unroll
        for (int tf = 0; tf < 4; ++tf)
#pragma unroll
          for (int i = 0; i < 4; ++i) {
            int t = t0 + tq * 64 + tf * 16 + q4 * 4 + i;
            if (t > s) sf[tq][tf][i] = -1e30f;
          }
    }
    // batched max over all 32 values
    float tm = -1e30f;
#pragma unroll
    for (int tq = 0; tq < 2; ++tq)
#pragma unroll
      for (int tf = 0; tf < 4; ++tf)
        tm = fmaxf(tm, fmaxf(fmaxf(sf[tq][tf][0], sf[tq][tf][1]),
                             fmaxf(sf[tq][tf][2], sf[tq][tf][3])));
    tm = fmaxf(tm, __shfl_xor(tm, 16));
    tm = fmaxf(tm, __shfl_xor(tm, 32));
    // defer-rescale (T13): skip O/l rescale while max drift <= 8 (log2)
    if (!__all(tm <= m_run + 8.f)) {
      float mn = fmaxf(m_run, tm);
      float alpha = exp2f(m_run - mn);
      m_run = mn;
      l_run *= alpha;
#pragma unroll
      for (int n2 = 0; n2 < 4; ++n2)
#pragma unroll
        for (int i = 0; i < 4; ++i) oacc[n2][i] *= alpha;
    }
    float rs = 0.f;
#pragma unroll
    for (int tq = 0; tq < 2; ++tq)
#pragma unroll
      for (int tf = 0; tf < 4; ++tf) {
        float p0 = exp2f(sf[tq][tf][0] - m_run);
        float p1 = exp2f(sf[tq][tf][1] - m_run);
        float p2 = exp2f(sf[tq][tf][2] - m_run);
        float p3 = exp2f(sf[tq][tf][3] - m_run);
        rs += (p0 + p1) + (p2 + p3);
        halfx4 pk;
        pk[0] = (_Float16)p0; pk[1] = (_Float16)p1;
        pk[2] = (_Float16)p2; pk[3] = (_Float16)p3;
        *(halfx4*)&Pw[(tq * 8 + tf * 2) * 128 + pwbase] = pk;
      }
    rs += __shfl_xor(rs, 16);
    rs += __shfl_xor(rs, 32);
    l_run += rs;
    // PV: O^T += V^T x P over 4 k-chunks of 32 t
    halfx8 bp[4];
#pragma unroll
    for (int kc = 0; kc < 4; ++kc)
      bp[kc] = *(const halfx8*)&Pw[kc * 512 + prbase];
    __builtin_amdgcn_s_setprio(1);
#pragma unroll
    for (int kc = 0; kc < 4; ++kc) {
      int half = (kc >> 1) * 64;
      int sw = ((q4 + 4 * (kc & 1)) ^ (ln & 7)) * 8;
#pragma unroll
      for (int n2 = 0; n2 < 4; ++n2) {
        halfx8 av = *(const halfx8*)&Vt[n2 * 16 + ln][half + sw];
        oacc[n2] = mfma16(av, bp[kc], oacc[n2]);
      }
    }
    __builtin_amdgcn_s_setprio(0);
  }
  // epilogue: O^T frag n2: h=ln, d=n2*16+q4*4+i (wave owns the full row)
  float inv = 1.0f / l_run;
#pragma unroll
  for (int n2 = 0; n2 < 4; ++n2) {
    halfx4 o;
#pragma unroll
    for (int i = 0; i < 4; ++i) o[i] = (_Float16)(oacc[n2][i] * inv);
    *(halfx4*)(aob + (bS + s) * DIM + ln * 64 + n2 * 16 + q4 * 4) = o;
  }
}

extern "C" void kernel_launch(void* const* d_in, const int* in_sizes, int n_in,
                              void* d_out, int out_size, void* d_ws,
                              size_t ws_size, hipStream_t stream) {
  const float* x    = (const float*)d_in[0];
  const float* wqkv = (const float*)d_in[1];
  const float* bqkv = (const float*)d_in[2];
  const float* wout = (const float*)d_in[3];
  const float* bout = (const float*)d_in[4];
  float* out = (float*)d_out;
  char* ws = (char*)d_ws;
  _Float16* xb    = (_Float16*)(ws);                               // 8 MB
  _Float16* qb    = (_Float16*)(ws + (8u << 20));                  // 8 MB
  _Float16* aob   = (_Float16*)(ws + (16u << 20));                 // 8 MB
  _Float16* kb    = (_Float16*)(ws + (24u << 20));                 // 512 KB
  _Float16* vtb   = (_Float16*)(ws + (24u << 20) + (512u << 10));  // 512 KB
  _Float16* wcomb = (_Float16*)(ws + (25u << 20));                 // 2.25 MB
  _Float16* woutb = (_Float16*)(ws + (27u << 20) + (512u << 10));  // 2 MB
  float*    bcomb = (float*)(ws + (29u << 20) + (512u << 10));     // 4.6 KB

  hipLaunchKernelGGL(prep_all, dim3(6656), dim3(256), 0, stream,
                     x, wqkv, bqkv, wout, xb, wcomb, woutb, bcomb);
  hipLaunchKernelGGL((gemm_t2<0>), dim3(32, 9), dim3(256), 0, stream,
                     xb, wcomb, bcomb, (void*)qb, kb, vtb);
  hipLaunchKernelGGL(flash_attn11, dim3(512), dim3(512), 0, stream,
                     qb, kb, vtb, aob);
  hipLaunchKernelGGL((gemm_t2<1>), dim3(32, 8), dim3(256), 0, stream,
                     aob, woutb, bout, (void*)out, nullptr, nullptr);
}

// Round 5
// 168.422 us; speedup vs baseline: 1.1613x; 1.0363x over previous
//
#include <hip/hip_runtime.h>

// Problem: B=2, S=2048, D=1024, H=16, HD=64. fp32 in/out.
// Pipeline exploits head-summed K/V: k_sum = x @ (sum_h Wk_h)^T + sum_h bk_h.
//  1. prep_all:    x, Wout -> f16; wcomb = [Wq; Wred] f16 (1152x1024); bcomb
//  2. gemm_t2<0>:  [Q*scale | k_sum | v_sum^T] = x @ wcomb^T + bcomb (N=1152)
//  3. flash_attn12: 8 rows/block, 1 wave = 1 full s-row, 128-t batched
//                  softmax; XCD-dispatch-aware pairing: co-resident blocks
//                  (i, i+256) carry 17 staging units together (uniform CUs)
//  4. gemm_t2<1>:  out = ao @ Wout^T + bout   (4096x1024x1024) -> f32

#define S_LEN 2048
#define DIM 1024

using floatx4 = __attribute__((ext_vector_type(4))) float;
using halfx8  = __attribute__((ext_vector_type(8))) _Float16;
using halfx4  = __attribute__((ext_vector_type(4))) _Float16;

__device__ __forceinline__ floatx4 mfma16(halfx8 a, halfx8 b, floatx4 c) {
  return __builtin_amdgcn_mfma_f32_16x16x32_f16(a, b, c, 0, 0, 0);
}

// async global->LDS, 16B per lane; lds dst is wave-uniform base + lane*16
__device__ __forceinline__ void gll16(const void* g, void* l) {
  __builtin_amdgcn_global_load_lds(
      (const __attribute__((address_space(1))) void*)g,
      (__attribute__((address_space(3))) void*)l, 16, 0, 0);
}

// ---------------- prep: conversions + combined weights ----------------
__global__ __launch_bounds__(256) void prep_all(
    const float* __restrict__ x, const float* __restrict__ wqkv,
    const float* __restrict__ bqkv, const float* __restrict__ wout,
    _Float16* __restrict__ xb, _Float16* __restrict__ wcomb,
    _Float16* __restrict__ woutb, float* __restrict__ bcomb) {
  int bx = blockIdx.x;
  if (bx < 6144) {
    size_t i4 = ((size_t)bx * 256 + threadIdx.x) * 4;
    const float* src;
    _Float16* dst;
    size_t off;
    if (i4 < 4194304) { src = x; dst = xb; off = i4; }
    else if (i4 < 5242880) { src = wqkv; dst = wcomb; off = i4 - 4194304; }
    else { src = wout; dst = woutb; off = i4 - 5242880; }
    float4 v = *(const float4*)(src + off);
    halfx4 o;
    o[0] = (_Float16)v.x; o[1] = (_Float16)v.y;
    o[2] = (_Float16)v.z; o[3] = (_Float16)v.w;
    *(halfx4*)(dst + off) = o;
  } else {
    int gid = (bx - 6144) * 256 + threadIdx.x;  // 131072 threads
    int c = gid >> 10, j = gid & 1023;
    int row0 = (c < 64) ? (1024 + c) : (2048 + c - 64);
    float s = 0.f;
#pragma unroll
    for (int h = 0; h < 16; ++h) s += wqkv[(size_t)(row0 + h * 64) * 1024 + j];
    wcomb[(size_t)1024 * 1024 + gid] = (_Float16)s;
    if (gid < 1024) bcomb[gid] = bqkv[gid];
    if (gid < 128) {
      int b0 = (gid < 64) ? (1024 + gid) : (2048 + gid - 64);
      float sb = 0.f;
#pragma unroll
      for (int h = 0; h < 16; ++h) sb += bqkv[b0 + h * 64];
      bcomb[1024 + gid] = sb;
    }
  }
}

// ------- gemm_t2: 128M x 128N tile (m97-style), BK=64, 2 barriers/step -----
// Wave w -> 64x64 quadrant: rows (w&1)*64, cols (w>>1)*64; 4x4 16x16 frags.
// gll16 staging with XOR col-group swizzle (row r group g at g^(r&7)).
// MODE 0: N=1152 fused epilogue -> qb (*scale), kb, vtb(V^T). MODE 1: f32 out.
template <int MODE>
__global__ __launch_bounds__(256, 2) void gemm_t2(
    const _Float16* __restrict__ A, const _Float16* __restrict__ W,
    const float* __restrict__ bias, void* __restrict__ Cv,
    _Float16* __restrict__ kbo, _Float16* __restrict__ vto) {
  const int K = 1024;
  __shared__ _Float16 As[128][64];  // 16 KB
  __shared__ _Float16 Ws[128][64];  // 16 KB
  int tid = threadIdx.x;
  int lane = tid & 63, w = tid >> 6, ln = lane & 15, q4 = lane >> 4;
  int m0 = blockIdx.x * 128, n0 = blockIdx.y * 128;
  int mh = (w & 1) * 64, nh = (w >> 1) * 64;
  int rr = lane >> 3, gg = ((lane & 7) ^ rr) * 8;  // staging lane row/col
  const _Float16* agp = A + (size_t)(m0 + w * 32 + rr) * K + gg;
  const _Float16* wgp = W + (size_t)(n0 + w * 32 + rr) * K + gg;
  floatx4 acc[4][4] = {};
  for (int kt = 0; kt < K; kt += 64) {
    __syncthreads();  // readers done with previous tile
#pragma unroll
    for (int j = 0; j < 4; ++j) {
      gll16(agp + (size_t)(8 * j) * K + kt, &As[w * 32 + 8 * j][0]);
      gll16(wgp + (size_t)(8 * j) * K + kt, &Ws[w * 32 + 8 * j][0]);
    }
    __syncthreads();  // staging visible
#pragma unroll
    for (int kh = 0; kh < 2; ++kh) {
      int sw = ((q4 + 4 * kh) ^ (ln & 7)) * 8;
      halfx8 bf[4];
#pragma unroll
      for (int nf = 0; nf < 4; ++nf)
        bf[nf] = *(const halfx8*)&Ws[nh + nf * 16 + ln][sw];
#pragma unroll
      for (int mf = 0; mf < 4; ++mf) {
        halfx8 af = *(const halfx8*)&As[mh + mf * 16 + ln][sw];
#pragma unroll
        for (int nf = 0; nf < 4; ++nf)
          acc[mf][nf] = mfma16(af, bf[nf], acc[mf][nf]);
      }
    }
  }
  const float qscale = 0.18033688011112042f;  // (1/sqrt(64)) * log2(e)
#pragma unroll
  for (int nf = 0; nf < 4; ++nf) {
    int col = n0 + nh + nf * 16 + ln;
    float bv = bias[col];
    if constexpr (MODE == 1) {
#pragma unroll
      for (int mf = 0; mf < 4; ++mf)
#pragma unroll
        for (int i = 0; i < 4; ++i) {
          int row = m0 + mh + mf * 16 + q4 * 4 + i;
          ((float*)Cv)[(size_t)row * 1024 + col] = acc[mf][nf][i] + bv;
        }
    } else {
      if (col < 1024) {  // Q, pre-scaled for log2-domain softmax
#pragma unroll
        for (int mf = 0; mf < 4; ++mf)
#pragma unroll
          for (int i = 0; i < 4; ++i) {
            int row = m0 + mh + mf * 16 + q4 * 4 + i;
            ((_Float16*)Cv)[(size_t)row * 1024 + col] =
                (_Float16)((acc[mf][nf][i] + bv) * qscale);
          }
      } else if (col < 1088) {  // k_sum
        int ck = col - 1024;
#pragma unroll
        for (int mf = 0; mf < 4; ++mf)
#pragma unroll
          for (int i = 0; i < 4; ++i) {
            int row = m0 + mh + mf * 16 + q4 * 4 + i;
            kbo[(size_t)row * 64 + ck] = (_Float16)(acc[mf][nf][i] + bv);
          }
      } else {  // v_sum, transposed: vtb[(b*64+d)*S + s]
        int d = col - 1088;
#pragma unroll
        for (int mf = 0; mf < 4; ++mf) {
          int row0 = m0 + mh + mf * 16 + q4 * 4;
          int bb = row0 >> 11, sps = row0 & 2047;
          halfx4 o;
#pragma unroll
          for (int i = 0; i < 4; ++i) o[i] = (_Float16)(acc[mf][nf][i] + bv);
          *(halfx4*)&vto[((size_t)((bb << 6) + d)) * S_LEN + sps] = o;
        }
      }
    }
  }
}

// ---------------- flash v12: XCD-dispatch-aware chunk pairing --------------
// Block = 8 consecutive s-rows (one chunk), 8 waves, 1 wave = 1 full s-row.
// Per 128-t staged tile: 16 QK MFMA -> batched softmax (31-fmax tree, 32
// exp2, single defer-check) -> 16 PV MFMA. P reader-linear in LDS.
// Dispatch model (confirmed r4: predicted 58.3 vs measured 58.8 us):
// block i -> XCD i%8; within an XCD blocks fill CUs sequentially, so blocks
// (i, i+256) are co-resident on one CU. Mapping: bx<256 -> crow=(bx&255)>>1
// (nt 1..8), bx>=256 -> crow=255-((bx&255)>>1) (nt 16..9). Co-resident work
// = 17 units for every i; bijective over 256 chunks x 2 batches.
__global__ __launch_bounds__(512, 4) void flash_attn12(
    const _Float16* __restrict__ Qb, const _Float16* __restrict__ kb,
    const _Float16* __restrict__ vtb, _Float16* __restrict__ aob) {
  __shared__ _Float16 Ks[128][64];   // 16 KB  K tile [t][d], XOR-swizzled
  __shared__ _Float16 Vt[64][128];   // 16 KB  V^T tile [d][t], per-64-half swz
  __shared__ _Float16 Ps[8][2048];   // 32 KB  per-wave P, reader-linear
  int tid = threadIdx.x;
  int lane = tid & 63, w = tid >> 6, ln = lane & 15, q4 = lane >> 4;
  int bx = (int)blockIdx.x;
  int lo = bx & 255;
  int b = lo & 1;                               // batch
  int crow = (bx >> 8) ? (255 - (lo >> 1)) : (lo >> 1);  // row-chunk
  int s0 = crow * 8;
  int s = s0 + w;
  size_t bS = (size_t)b * S_LEN;

  // K staging: wave w covers t-rows w*16..+15; lane: row += lane>>3, grp^row
  int rr = lane >> 3, ggk = ((lane & 7) ^ rr) * 8;
  const _Float16* kgp = kb + (bS + w * 16 + rr) * 64 + ggk;
  // V staging: wave w covers d-rows w*8..+7; lane: row += lane>>4,
  // t-col = half*64 + (vg ^ (row&7))*8, vg = lane&7, half = (lane>>3)&1
  int vr = lane >> 4;
  int vhalf = (lane >> 3) & 1, vg = lane & 7;
  const _Float16* vgp[2];
#pragma unroll
  for (int j = 0; j < 2; ++j) {
    int row = w * 8 + 4 * j + vr;
    vgp[j] = vtb + ((size_t)b * 64 + row) * S_LEN + vhalf * 64 +
             ((vg ^ (row & 7)) * 8);
  }
  int swk0 = (q4 ^ (ln & 7)) * 8;
  int swk1 = ((q4 + 4) ^ (ln & 7)) * 8;
  _Float16* Pw = &Ps[w][0];
  // P write (halfx4): half-idx = (tq*8+tf*2)*128 + pwbase
  int pwbase = (q4 >> 1) * 128 + ln * 8 + (q4 & 1) * 4;
  // P read (halfx8): half-idx = kc*512 + prbase  (lane-linear)
  int prbase = q4 * 128 + ln * 8;

  const _Float16* qp = Qb + (bS + s) * DIM + ln * 64 + q4 * 8;
  halfx8 bq0 = *(const halfx8*)qp, bq1 = *(const halfx8*)(qp + 32);

  float m_run = -1e30f, l_run = 0.f;
  floatx4 oacc[4] = {};
  int nt = (crow >> 4) + 1;

  for (int it = 0; it < nt; ++it) {
    int t0 = it << 7;
    __syncthreads();
    gll16(kgp + (size_t)t0 * 64, &Ks[w * 16][0]);
    gll16(kgp + (size_t)(t0 + 8) * 64, &Ks[w * 16 + 8][0]);
    gll16(vgp[0] + t0, &Vt[w * 8][0]);
    gll16(vgp[1] + t0, &Vt[w * 8 + 4][0]);
    __syncthreads();

    // S^T = K Q^T (log2 domain): frag (tq,tf) rows t = t0+tq*64+tf*16+ln
    floatx4 sf[2][4];
    __builtin_amdgcn_s_setprio(1);
#pragma unroll
    for (int tq = 0; tq < 2; ++tq)
#pragma unroll
      for (int tf = 0; tf < 4; ++tf) {
        halfx8 ak0 = *(const halfx8*)&Ks[tq * 64 + tf * 16 + ln][swk0];
        halfx8 ak1 = *(const halfx8*)&Ks[tq * 64 + tf * 16 + ln][swk1];
        floatx4 z = {};
        z = mfma16(ak0, bq0, z);
        sf[tq][tf] = mfma16(ak1, bq1, z);
      }
    __builtin_amdgcn_s_setprio(0);
    if (it == nt - 1) {  // causal mask (block-uniform: only final tile)
#pragma unroll
      for (int tq = 0; tq < 2; ++tq)
#pragma unroll
        for (int tf = 0; tf < 4; ++tf)
#pragma unroll
          for (int i = 0; i < 4; ++i) {
            int t = t0 + tq * 64 + tf * 16 + q4 * 4 + i;
            if (t > s) sf[tq][tf][i] = -1e30f;
          }
    }
    // batched max over all 32 values
    float tm = -1e30f;
#pragma unroll
    for (int tq = 0; tq < 2; ++tq)
#pragma unroll
      for (int tf = 0; tf < 4; ++tf)
        tm = fmaxf(tm, fmaxf(fmaxf(sf[tq][tf][0], sf[tq][tf][1]),
                             fmaxf(sf[tq][tf][2], sf[tq][tf][3])));
    tm = fmaxf(tm, __shfl_xor(tm, 16));
    tm = fmaxf(tm, __shfl_xor(tm, 32));
    // defer-rescale (T13): skip O/l rescale while max drift <= 8 (log2)
    if (!__all(tm <= m_run + 8.f)) {
      float mn = fmaxf(m_run, tm);
      float alpha = exp2f(m_run - mn);
      m_run = mn;
      l_run *= alpha;
#pragma unroll
      for (int n2 = 0; n2 < 4; ++n2)
#pragma unroll
        for (int i = 0; i < 4; ++i) oacc[n2][i] *= alpha;
    }
    float rs = 0.f;
#pragma unroll
    for (int tq = 0; tq < 2; ++tq)
#pragma unroll
      for (int tf = 0; tf < 4; ++tf) {
        float p0 = exp2f(sf[tq][tf][0] - m_run);
        float p1 = exp2f(sf[tq][tf][1] - m_run);
        float p2 = exp2f(sf[tq][tf][2] - m_run);
        float p3 = exp2f(sf[tq][tf][3] - m_run);
        rs += (p0 + p1) + (p2 + p3);
        halfx4 pk;
        pk[0] = (_Float16)p0; pk[1] = (_Float16)p1;
        pk[2] = (_Float16)p2; pk[3] = (_Float16)p3;
        *(halfx4*)&Pw[(tq * 8 + tf * 2) * 128 + pwbase] = pk;
      }
    rs += __shfl_xor(rs, 16);
    rs += __shfl_xor(rs, 32);
    l_run += rs;
    // PV: O^T += V^T x P over 4 k-chunks of 32 t
    halfx8 bp[4];
#pragma unroll
    for (int kc = 0; kc < 4; ++kc)
      bp[kc] = *(const halfx8*)&Pw[kc * 512 + prbase];
    __builtin_amdgcn_s_setprio(1);
#pragma unroll
    for (int kc = 0; kc < 4; ++kc) {
      int half = (kc >> 1) * 64;
      int sw = ((q4 + 4 * (kc & 1)) ^ (ln & 7)) * 8;
#pragma unroll
      for (int n2 = 0; n2 < 4; ++n2) {
        halfx8 av = *(const halfx8*)&Vt[n2 * 16 + ln][half + sw];
        oacc[n2] = mfma16(av, bp[kc], oacc[n2]);
      }
    }
    __builtin_amdgcn_s_setprio(0);
  }
  // epilogue: O^T frag n2: h=ln, d=n2*16+q4*4+i (wave owns the full row)
  float inv = 1.0f / l_run;
#pragma unroll
  for (int n2 = 0; n2 < 4; ++n2) {
    halfx4 o;
#pragma unroll
    for (int i = 0; i < 4; ++i) o[i] = (_Float16)(oacc[n2][i] * inv);
    *(halfx4*)(aob + (bS + s) * DIM + ln * 64 + n2 * 16 + q4 * 4) = o;
  }
}

extern "C" void kernel_launch(void* const* d_in, const int* in_sizes, int n_in,
                              void* d_out, int out_size, void* d_ws,
                              size_t ws_size, hipStream_t stream) {
  const float* x    = (const float*)d_in[0];
  const float* wqkv = (const float*)d_in[1];
  const float* bqkv = (const float*)d_in[2];
  const float* wout = (const float*)d_in[3];
  const float* bout = (const float*)d_in[4];
  float* out = (float*)d_out;
  char* ws = (char*)d_ws;
  _Float16* xb    = (_Float16*)(ws);                               // 8 MB
  _Float16* qb    = (_Float16*)(ws + (8u << 20));                  // 8 MB
  _Float16* aob   = (_Float16*)(ws + (16u << 20));                 // 8 MB
  _Float16* kb    = (_Float16*)(ws + (24u << 20));                 // 512 KB
  _Float16* vtb   = (_Float16*)(ws + (24u << 20) + (512u << 10));  // 512 KB
  _Float16* wcomb = (_Float16*)(ws + (25u << 20));                 // 2.25 MB
  _Float16* woutb = (_Float16*)(ws + (27u << 20) + (512u << 10));  // 2 MB
  float*    bcomb = (float*)(ws + (29u << 20) + (512u << 10));     // 4.6 KB

  hipLaunchKernelGGL(prep_all, dim3(6656), dim3(256), 0, stream,
                     x, wqkv, bqkv, wout, xb, wcomb, woutb, bcomb);
  hipLaunchKernelGGL((gemm_t2<0>), dim3(32, 9), dim3(256), 0, stream,
                     xb, wcomb, bcomb, (void*)qb, kb, vtb);
  hipLaunchKernelGGL(flash_attn12, dim3(512), dim3(512), 0, stream,
                     qb, kb, vtb, aob);
  hipLaunchKernelGGL((gemm_t2<1>), dim3(32, 8), dim3(256), 0, stream,
                     aob, woutb, bout, (void*)out, nullptr, nullptr);
}